// Round 1
// baseline (131.100 us; speedup 1.0000x reference)
//
#include <hip/hip_runtime.h>

#define R_RAYS 16384
#define S_VALS 64
#define NSAMP 128
#define M_BINS 63        // z_half entries (= cdf entries)
#define NW 62            // weights used per ray (S-2)
#define Z_ALL 192
#define WEPS 1e-5f

__global__ __launch_bounds__(256) void ray_sampler_kernel(
    const float* __restrict__ rays_d,
    const float* __restrict__ rays_o,
    const float* __restrict__ z_vals,
    const float* __restrict__ weights,
    float* __restrict__ pts_out,
    float* __restrict__ zall_out)
{
    __shared__ float s_zh[4][64];     // z_half bins (63 used)
    __shared__ float s_cdf[4][64];    // cdf (63 used)
    __shared__ float s_smp[4][NSAMP]; // sorted samples
    __shared__ float s_zv[4][64];     // z_vals
    __shared__ float s_za[4][Z_ALL];  // merged output

    const int wid  = threadIdx.x >> 6;
    const int lane = threadIdx.x & 63;
    const int ray  = blockIdx.x * 4 + wid;       // ray = b*R + r
    const int r    = ray & (R_RAYS - 1);

    // ---- stage z_vals + z_half ----
    float zv = z_vals[r * S_VALS + lane];
    s_zv[wid][lane] = zv;
    float znext = __shfl_down(zv, 1);
    if (lane < M_BINS) s_zh[wid][lane] = 0.5f * (zv + znext);

    // ---- cdf: weights[...,1:-1] + eps, normalize, inclusive scan ----
    float w = 0.0f;
    if (lane < NW) w = weights[(size_t)ray * S_VALS + lane + 1] + WEPS;
    float ws = w;
    #pragma unroll
    for (int off = 32; off; off >>= 1) ws += __shfl_xor(ws, off);
    float pdf = w / ws;
    float sc = pdf;
    #pragma unroll
    for (int off = 1; off < 64; off <<= 1) {
        float y = __shfl_up(sc, off);
        if (lane >= off) sc += y;
    }
    if (lane == 0) s_cdf[wid][0] = 0.0f;
    if (lane < NW) s_cdf[wid][lane + 1] = sc;
    __syncthreads();

    // ---- inverse-CDF sample 128 u's (2 per lane) ----
    const float* cdf = s_cdf[wid];
    const float* zh  = s_zh[wid];
    #pragma unroll
    for (int t = 0; t < 2; ++t) {
        int ui = lane + 64 * t;
        float u = (float)ui * (1.0f / 127.0f);
        if (ui == NSAMP - 1) u = 1.0f;
        // searchsorted side='right': first index with cdf > u
        int lo = 0, hi = M_BINS;
        while (lo < hi) {
            int mid = (lo + hi) >> 1;
            if (cdf[mid] <= u) lo = mid + 1; else hi = mid;
        }
        int below = lo - 1;                       // lo >= 1 (cdf[0]=0 <= u)
        int above = (lo < M_BINS) ? lo : (M_BINS - 1);
        float clo = cdf[below], chi = cdf[above];
        float blo = zh[below],  bhi = zh[above];
        float denom = chi - clo;
        if (denom < 1e-5f) denom = 1.0f;
        float tt = (u - clo) / denom;
        s_smp[wid][ui] = fmaf(tt, bhi - blo, blo);
    }
    __syncthreads();

    // ---- merge (both lists sorted) via ranks ----
    const float* smp = s_smp[wid];
    const float* zvs = s_zv[wid];
    {   // z_vals element: rank = lane + count(samples < zv)
        int lo = 0, hi = NSAMP;
        while (lo < hi) {
            int mid = (lo + hi) >> 1;
            if (smp[mid] < zv) lo = mid + 1; else hi = mid;
        }
        s_za[wid][lane + lo] = zv;
    }
    #pragma unroll
    for (int t = 0; t < 2; ++t) {   // sample: rank = j + count(zvals <= s)
        int j = lane + 64 * t;
        float v = smp[j];
        int lo = 0, hi = S_VALS;
        while (lo < hi) {
            int mid = (lo + hi) >> 1;
            if (zvs[mid] <= v) lo = mid + 1; else hi = mid;
        }
        s_za[wid][j + lo] = v;
    }
    __syncthreads();

    // ---- write z_all ----
    const size_t zbase = (size_t)ray * Z_ALL;
    #pragma unroll
    for (int t = 0; t < 3; ++t)
        zall_out[zbase + lane + 64 * t] = s_za[wid][lane + 64 * t];

    // ---- write pts = o + d*z, coalesced dword stream ----
    float ox = rays_o[ray * 3 + 0], oy = rays_o[ray * 3 + 1], oz = rays_o[ray * 3 + 2];
    float dx = rays_d[ray * 3 + 0], dy = rays_d[ray * 3 + 1], dz = rays_d[ray * 3 + 2];
    const size_t pbase = (size_t)ray * (Z_ALL * 3);
    #pragma unroll
    for (int t = 0; t < 9; ++t) {
        int k = lane + 64 * t;
        int s = k / 3;
        int c = k - s * 3;
        float z = s_za[wid][s];
        float o = (c == 0) ? ox : ((c == 1) ? oy : oz);
        float d = (c == 0) ? dx : ((c == 1) ? dy : dz);
        pts_out[pbase + k] = fmaf(d, z, o);
    }
}

extern "C" void kernel_launch(void* const* d_in, const int* in_sizes, int n_in,
                              void* d_out, int out_size, void* d_ws, size_t ws_size,
                              hipStream_t stream) {
    const float* rays_d  = (const float*)d_in[0];
    const float* rays_o  = (const float*)d_in[1];
    const float* z_vals  = (const float*)d_in[2];
    const float* weights = (const float*)d_in[3];

    float* pts  = (float*)d_out;                       // (8,16384,192,3)
    float* zall = pts + (size_t)8 * 16384 * 192 * 3;   // (8,16384,192)

    const int total_rays = 8 * 16384;                  // 131072
    dim3 grid(total_rays / 4), block(256);
    ray_sampler_kernel<<<grid, block, 0, stream>>>(rays_d, rays_o, z_vals,
                                                   weights, pts, zall);
}

// Round 3
// 117.798 us; speedup vs baseline: 1.1129x; 1.1129x over previous
//
#include <hip/hip_runtime.h>

#define R_RAYS 16384
#define S_VALS 64
#define NSAMP 128
#define M_BINS 63        // z_half entries (= cdf entries)
#define NW 62            // weights used per ray (S-2)
#define Z_ALL 192
#define WEPS 1e-5f

typedef float f32x4 __attribute__((ext_vector_type(4)));

__global__ __launch_bounds__(256) void ray_sampler_kernel(
    const float* __restrict__ rays_d,
    const float* __restrict__ rays_o,
    const float* __restrict__ z_vals,
    const float* __restrict__ weights,
    float* __restrict__ pts_out,
    float* __restrict__ zall_out)
{
    __shared__ float s_zh[4][64];                   // z_half bins (63 used)
    __shared__ float s_cdf[4][64];                  // cdf (63 used)
    __shared__ float s_smp[4][NSAMP];               // sorted samples
    __shared__ float s_zv[4][64];                   // z_vals
    __shared__ __align__(16) float s_za[4][Z_ALL];  // merged output
    __shared__ float s_od[4][6];                    // ox,oy,oz,dx,dy,dz per ray

    const int wid  = threadIdx.x >> 6;
    const int lane = threadIdx.x & 63;
    const int ray  = blockIdx.x * 4 + wid;       // ray = b*R + r
    const int r    = ray & (R_RAYS - 1);

    // ---- stage o/d for the store phase ----
    if (lane < 6)
        s_od[wid][lane] = (lane < 3) ? rays_o[ray * 3 + lane]
                                     : rays_d[ray * 3 + lane - 3];

    // ---- stage z_vals + z_half ----
    float zv = z_vals[r * S_VALS + lane];
    s_zv[wid][lane] = zv;
    float znext = __shfl_down(zv, 1);
    if (lane < M_BINS) s_zh[wid][lane] = 0.5f * (zv + znext);

    // ---- cdf: weights[...,1:-1] + eps, normalize, inclusive scan ----
    float w = 0.0f;
    if (lane < NW) w = weights[(size_t)ray * S_VALS + lane + 1] + WEPS;
    float ws = w;
    #pragma unroll
    for (int off = 32; off; off >>= 1) ws += __shfl_xor(ws, off);
    float pdf = w / ws;
    float sc = pdf;
    #pragma unroll
    for (int off = 1; off < 64; off <<= 1) {
        float y = __shfl_up(sc, off);
        if (lane >= off) sc += y;
    }
    if (lane == 0) s_cdf[wid][0] = 0.0f;
    if (lane < NW) s_cdf[wid][lane + 1] = sc;
    // (no __syncthreads: each wave only reads its own LDS slices below;
    //  within-wave LDS write->read ordering is handled by lgkmcnt)

    // ---- inverse-CDF sample 128 u's (2 per lane) ----
    const float* cdf = s_cdf[wid];
    const float* zh  = s_zh[wid];
    #pragma unroll
    for (int t = 0; t < 2; ++t) {
        int ui = lane + 64 * t;
        float u = (float)ui * (1.0f / 127.0f);
        if (ui == NSAMP - 1) u = 1.0f;
        // searchsorted side='right': first index with cdf > u
        int lo = 0, hi = M_BINS;
        while (lo < hi) {
            int mid = (lo + hi) >> 1;
            if (cdf[mid] <= u) lo = mid + 1; else hi = mid;
        }
        int below = lo - 1;                       // lo >= 1 (cdf[0]=0 <= u)
        int above = (lo < M_BINS) ? lo : (M_BINS - 1);
        float clo = cdf[below], chi = cdf[above];
        float blo = zh[below],  bhi = zh[above];
        float denom = chi - clo;
        if (denom < 1e-5f) denom = 1.0f;
        float tt = (u - clo) / denom;
        s_smp[wid][ui] = fmaf(tt, bhi - blo, blo);
    }

    // ---- merge (both lists sorted) via ranks ----
    const float* smp = s_smp[wid];
    const float* zvs = s_zv[wid];
    {   // z_vals element: rank = lane + count(samples < zv)
        int lo = 0, hi = NSAMP;
        while (lo < hi) {
            int mid = (lo + hi) >> 1;
            if (smp[mid] < zv) lo = mid + 1; else hi = mid;
        }
        s_za[wid][lane + lo] = zv;
    }
    #pragma unroll
    for (int t = 0; t < 2; ++t) {   // sample: rank = j + count(zvals <= s)
        int j = lane + 64 * t;
        float v = smp[j];
        int lo = 0, hi = S_VALS;
        while (lo < hi) {
            int mid = (lo + hi) >> 1;
            if (zvs[mid] <= v) lo = mid + 1; else hi = mid;
        }
        s_za[wid][j + lo] = v;
    }
    __syncthreads();   // the ONLY barrier: store phase reads other waves' rays

    // ---- block-cooperative vectorized drain ----
    // per block: pts = 4*192*3 = 2304 floats = 576 float4 (contiguous),
    //            z_all = 4*192 = 768 floats  = 192 float4 (contiguous).
    // 768 float4 total = 3 per thread; idx<576 split is wave-uniform.
    const size_t pbase = (size_t)blockIdx.x * (4 * Z_ALL * 3);
    const size_t zbase = (size_t)blockIdx.x * (4 * Z_ALL);
    #pragma unroll
    for (int t = 0; t < 3; ++t) {
        int idx = t * 256 + threadIdx.x;          // 0..767
        if (idx < 576) {
            int f0 = idx * 4;                     // float offset in block pts
            int rl = f0 / 576;                    // local ray 0..3
            int g  = f0 - rl * 576;               // 0..572, multiple of 4
            int s0 = g / 3;
            float z0 = s_za[rl][s0];
            float z1 = s_za[rl][s0 + 1];
            float ox = s_od[rl][0], oy = s_od[rl][1], oz = s_od[rl][2];
            float dx = s_od[rl][3], dy = s_od[rl][4], dz = s_od[rl][5];
            f32x4 v;
            #pragma unroll
            for (int i = 0; i < 4; ++i) {
                int gi = g + i;
                int s  = gi / 3;
                int c  = gi - s * 3;
                float z = (s == s0) ? z0 : z1;
                float o = (c == 0) ? ox : ((c == 1) ? oy : oz);
                float d = (c == 0) ? dx : ((c == 1) ? dy : dz);
                v[i] = fmaf(d, z, o);
            }
            __builtin_nontemporal_store(v, (f32x4*)(pts_out + pbase + f0));
        } else {
            int j  = idx - 576;                   // 0..191
            int rl = j / 48;
            int s4 = (j - rl * 48) * 4;
            f32x4 v = *(const f32x4*)&s_za[rl][s4];
            __builtin_nontemporal_store(v, (f32x4*)(zall_out + zbase + j * 4));
        }
    }
}

extern "C" void kernel_launch(void* const* d_in, const int* in_sizes, int n_in,
                              void* d_out, int out_size, void* d_ws, size_t ws_size,
                              hipStream_t stream) {
    const float* rays_d  = (const float*)d_in[0];
    const float* rays_o  = (const float*)d_in[1];
    const float* z_vals  = (const float*)d_in[2];
    const float* weights = (const float*)d_in[3];

    float* pts  = (float*)d_out;                       // (8,16384,192,3)
    float* zall = pts + (size_t)8 * 16384 * 192 * 3;   // (8,16384,192)

    const int total_rays = 8 * 16384;                  // 131072
    dim3 grid(total_rays / 4), block(256);
    ray_sampler_kernel<<<grid, block, 0, stream>>>(rays_d, rays_o, z_vals,
                                                   weights, pts, zall);
}

// Round 4
// 116.529 us; speedup vs baseline: 1.1250x; 1.0109x over previous
//
#include <hip/hip_runtime.h>

#define R_RAYS 16384
#define S_VALS 64
#define NSAMP 128
#define M_BINS 63        // z_half entries (= cdf entries)
#define NW 62            // weights used per ray (S-2)
#define Z_ALL 192
#define WEPS 1e-5f

typedef float f32x4 __attribute__((ext_vector_type(4)));

__global__ __launch_bounds__(256, 8) void ray_sampler_kernel(
    const float* __restrict__ rays_d,
    const float* __restrict__ rays_o,
    const float* __restrict__ z_vals,
    const float* __restrict__ weights,
    float* __restrict__ pts_out,
    float* __restrict__ zall_out)
{
    __shared__ float s_zh[4][64];                   // z_half bins (63 used)
    __shared__ float s_cdf[4][64];                  // cdf (63 used)
    __shared__ float s_smp[4][NSAMP];               // sorted samples
    __shared__ float s_zv[4][64];                   // z_vals
    __shared__ __align__(16) float s_za[4][Z_ALL];  // merged output

    const int wid  = threadIdx.x >> 6;
    const int lane = threadIdx.x & 63;
    const int ray  = blockIdx.x * 4 + wid;       // ray = b*R + r
    const int r    = ray & (R_RAYS - 1);

    // ---- stage z_vals + z_half ----
    float zv = z_vals[r * S_VALS + lane];
    s_zv[wid][lane] = zv;
    float znext = __shfl_down(zv, 1);
    if (lane < M_BINS) s_zh[wid][lane] = 0.5f * (zv + znext);

    // ---- cdf: weights[...,1:-1] + eps, normalize, inclusive scan ----
    float w = 0.0f;
    if (lane < NW) w = weights[(size_t)ray * S_VALS + lane + 1] + WEPS;
    float ws = w;
    #pragma unroll
    for (int off = 32; off; off >>= 1) ws += __shfl_xor(ws, off);
    float pdf = w / ws;
    float sc = pdf;
    #pragma unroll
    for (int off = 1; off < 64; off <<= 1) {
        float y = __shfl_up(sc, off);
        if (lane >= off) sc += y;
    }
    if (lane == 0) s_cdf[wid][0] = 0.0f;
    if (lane < NW) s_cdf[wid][lane + 1] = sc;
    // no __syncthreads anywhere: every wave touches only s_*[wid]

    // ---- inverse-CDF sample 128 u's (2 per lane), branchless search ----
    const float* cdf = s_cdf[wid];
    const float* zh  = s_zh[wid];
    #pragma unroll
    for (int t = 0; t < 2; ++t) {
        int ui = lane + 64 * t;
        float u = (float)ui * (1.0f / 127.0f);
        if (ui == NSAMP - 1) u = 1.0f;
        // branchless searchsorted-right over 63 cdf entries: T = #(cdf <= u)
        int pos = 0;
        #pragma unroll
        for (int s = 32; s >= 1; s >>= 1) {       // 32+16+8+4+2+1 = 63
            int np = pos + s;                     // np <= 63, read idx <= 62
            pos = (cdf[np - 1] <= u) ? np : pos;
        }
        int below = pos - 1;                      // pos >= 1 (cdf[0]=0 <= u)
        int above = (pos < M_BINS) ? pos : (M_BINS - 1);
        float clo = cdf[below], chi = cdf[above];
        float blo = zh[below],  bhi = zh[above];
        float denom = chi - clo;
        if (denom < 1e-5f) denom = 1.0f;
        float tt = (u - clo) / denom;
        s_smp[wid][ui] = fmaf(tt, bhi - blo, blo);
    }

    // ---- merge (both lists sorted) via branchless ranks ----
    const float* smp = s_smp[wid];
    const float* zvs = s_zv[wid];
    {   // z_vals element: rank = lane + #(samples < zv), T in [0,128]
        int pos = 0;
        #pragma unroll
        for (int s = 64; s >= 1; s >>= 1) {
            int np = pos + s;
            pos = (smp[np - 1] < zv) ? np : pos;
        }
        {   // extra 1-step covers T = 128
            int np = pos + 1;
            pos = (np <= NSAMP && smp[np - 1] < zv) ? np : pos;
        }
        s_za[wid][lane + pos] = zv;
    }
    #pragma unroll
    for (int t = 0; t < 2; ++t) {   // sample: rank = j + #(zvals <= s), T in [0,64]
        int j = lane + 64 * t;
        float v = smp[j];
        int pos = 0;
        #pragma unroll
        for (int s = 32; s >= 1; s >>= 1) {
            int np = pos + s;
            pos = (zvs[np - 1] <= v) ? np : pos;
        }
        {   // extra 1-step covers T = 64
            int np = pos + 1;
            pos = (np <= S_VALS && zvs[np - 1] <= v) ? np : pos;
        }
        s_za[wid][j + pos] = v;
    }

    // ---- per-wave vectorized drain (no barrier) ----
    // per ray: pts = 192*3 = 576 floats = 144 float4; z_all = 48 float4.
    // 192 float4 total = 3 per lane.
    const float* za = s_za[wid];
    float ox = rays_o[ray * 3 + 0], oy = rays_o[ray * 3 + 1], oz = rays_o[ray * 3 + 2];
    float dx = rays_d[ray * 3 + 0], dy = rays_d[ray * 3 + 1], dz = rays_d[ray * 3 + 2];
    const size_t pbase = (size_t)ray * (Z_ALL * 3);
    const size_t zbase = (size_t)ray * Z_ALL;
    #pragma unroll
    for (int t = 0; t < 3; ++t) {
        int idx = lane + 64 * t;                  // 0..191
        if (idx < 144) {
            int f0 = idx * 4;                     // 0..572
            int s0 = f0 / 3;
            float z0 = za[s0];
            float z1 = za[s0 + 1];
            f32x4 v;
            #pragma unroll
            for (int i = 0; i < 4; ++i) {
                int gi = f0 + i;
                int s  = gi / 3;
                int c  = gi - s * 3;
                float z = (s == s0) ? z0 : z1;
                float o = (c == 0) ? ox : ((c == 1) ? oy : oz);
                float d = (c == 0) ? dx : ((c == 1) ? dy : dz);
                v[i] = fmaf(d, z, o);
            }
            *(f32x4*)(pts_out + pbase + f0) = v;
        } else {
            int j = idx - 144;                    // 0..47
            f32x4 v = *(const f32x4*)&za[j * 4];
            *(f32x4*)(zall_out + zbase + j * 4) = v;
        }
    }
}

extern "C" void kernel_launch(void* const* d_in, const int* in_sizes, int n_in,
                              void* d_out, int out_size, void* d_ws, size_t ws_size,
                              hipStream_t stream) {
    const float* rays_d  = (const float*)d_in[0];
    const float* rays_o  = (const float*)d_in[1];
    const float* z_vals  = (const float*)d_in[2];
    const float* weights = (const float*)d_in[3];

    float* pts  = (float*)d_out;                       // (8,16384,192,3)
    float* zall = pts + (size_t)8 * 16384 * 192 * 3;   // (8,16384,192)

    const int total_rays = 8 * 16384;                  // 131072
    dim3 grid(total_rays / 4), block(256);
    ray_sampler_kernel<<<grid, block, 0, stream>>>(rays_d, rays_o, z_vals,
                                                   weights, pts, zall);
}